// Round 10
// baseline (136.223 us; speedup 1.0000x reference)
//
#include <hip/hip_runtime.h>
#include <hip/hip_bf16.h>

// Problem constants
#define BB 4
#define LL 4096
#define DD 256
#define MM (BB * LL)              // 16384 rows total
#define NSPLIT 8
#define BM 256                    // query rows per attn block (4 waves x 64 rows)
#define NQB (LL / BM)             // 16 query blocks per batch
#define KPS (LL / NSPLIT)         // 512 keys per split
#define KT 64                     // keys per LDS tile (64 x 512B = 32KB)
#define NKT (KPS / KT)            // 8

typedef short short8 __attribute__((ext_vector_type(8)));   // 8 bf16 (4 VGPRs)
typedef float floatx4 __attribute__((ext_vector_type(4)));

#define SCALE_LOG2E 14.426950408889634f   // INV_TEMP * log2(e)

// Fragment-major layout (qn, kn, W all use it): for 16-row group g, the 16B
// chunk holding row (g*16+n15), k-bytes [kk*64+quad*16, +16) lives at byte
//   g*8192 + kk*1024 + quad*256 + n15*16  ==  g*8192 + kk*1024 + lane*16.
// A wave's ds_read_b128 of one kk-slice is lane-linear stride-16 (contiguous
// 1KB) -> the m97 GEMM bank pattern, zero conflicts (verified R9: win).

__device__ __forceinline__ unsigned short f2bf(float f) {
    __hip_bfloat16 h = __float2bfloat16(f);
    union { __hip_bfloat16 h; unsigned short s; } c; c.h = h; return c.s;
}

__device__ __forceinline__ float fast_exp2(float x) {
#if __has_builtin(__builtin_amdgcn_exp2f)
    return __builtin_amdgcn_exp2f(x);
#else
    return exp2f(x);
#endif
}

// Pin a 128-bit fragment in VGPRs (defeats load-sinking/remat: round-3 showed
// the compiler re-loads Q from global inside the K-loop otherwise).
__device__ __forceinline__ void pinv(short8& v) {
    asm volatile("" : "+v"(v));
}

// Stage 16B/lane global -> LDS (wave-uniform LDS base; lane i -> l + i*16).
__device__ __forceinline__ void stage16(const char* g, char* l, int lane) {
#if __has_builtin(__builtin_amdgcn_global_load_lds)
    __builtin_amdgcn_global_load_lds(
        (const __attribute__((address_space(1))) void*)(g + lane * 16),
        (__attribute__((address_space(3))) void*)l, 16, 0, 0);
#else
    *(short8*)(l + lane * 16) = *(const short8*)(g + lane * 16);
#endif
}

// ---------------------------------------------------------------------------
// Kernel 0: W f32 -> bf16 FRAGMENT-MAJOR. Blocks 0..31 -> Wq, 32..63 -> Wk.
// Thread t handles row r=t>>5, 8-col chunk c=t&31 (= kk*4+quad).
// ---------------------------------------------------------------------------
__global__ __launch_bounds__(256) void cvt_fm_kernel(
    const float* __restrict__ srcq, const float* __restrict__ srck,
    unsigned short* __restrict__ dstq, unsigned short* __restrict__ dstk)
{
    const int which = blockIdx.x >> 5;
    const float* src = which ? srck : srcq;
    unsigned short* dst = which ? dstk : dstq;
    const int t = (blockIdx.x & 31) * 256 + threadIdx.x;
    const int r = t >> 5, c = t & 31;
    const float4 v0 = ((const float4*)src)[t * 2];
    const float4 v1 = ((const float4*)src)[t * 2 + 1];
    short8 o;
    o[0] = (short)f2bf(v0.x); o[1] = (short)f2bf(v0.y);
    o[2] = (short)f2bf(v0.z); o[3] = (short)f2bf(v0.w);
    o[4] = (short)f2bf(v1.x); o[5] = (short)f2bf(v1.y);
    o[6] = (short)f2bf(v1.z); o[7] = (short)f2bf(v1.w);
    // chunk index = ((r>>4)*8 + kk)*4*16 + quad*16 + n15, with c = kk*4+quad
    const int chunk = (r >> 4) * 512 + c * 16 + (r & 15);
    *(short8*)(dst + (size_t)chunk * 8) = o;
}

// ---------------------------------------------------------------------------
// Kernel A: one pass (q or k) per block; 512 blocks = (row-block of 64, pass).
// Pass/pair XCD swizzle: pass = (bid>>3)&1, pair = (bid&7)|((bid>>4)<<3) ->
// the q-block and k-block of the same 64 rows land on the SAME XCD 8 ids
// apart, so the second latents read is an L2 hit (halves latents HBM).
// W staged through LDS (double-buffered, global_load_lds) from fragment-major
// W; B-fragment ds_reads are lane-linear (conflict-free).
// qn = l2norm(lat @ Wq^T)*SCALE_LOG2E, kn = l2norm(lat @ Wk^T); BOTH stored
// fragment-major via the same (verified) transpose epilogue.
// MFMA 16x16x32 bf16; C/D: col=lane&15, row=quad*4+reg.
// ---------------------------------------------------------------------------
__global__ __launch_bounds__(256) void proj_norm_kernel(
    const float* __restrict__ latents,
    const __hip_bfloat16* __restrict__ Wq,
    const __hip_bfloat16* __restrict__ Wk,
    __hip_bfloat16* __restrict__ qn,
    __hip_bfloat16* __restrict__ kn)
{
    __shared__ char lds[65536];   // 2 x 32KB W double-buffer; reused for transpose

    const int tid  = threadIdx.x;
    const int wave = tid >> 6;
    const int lane = tid & 63;
    const int n15  = lane & 15;
    const int quad = lane >> 4;

    const int pass  = (blockIdx.x >> 3) & 1;
    const int pidx  = (blockIdx.x & 7) | ((blockIdx.x >> 4) << 3);
    const int rbase = pidx * 64;
    const int m0    = rbase + wave * 16;
    const int r160  = rbase >> 4;

    // A fragments: 16 rows x K=256, f32 loaded, converted in-register
    short8 afrag[8];
    const float* Abase = latents + (size_t)(m0 + n15) * DD + quad * 8;
#pragma unroll
    for (int kk = 0; kk < 8; ++kk) {
        const float4 v0 = *(const float4*)(Abase + kk * 32);
        const float4 v1 = *(const float4*)(Abase + kk * 32 + 4);
        short8 f;
        f[0] = (short)f2bf(v0.x); f[1] = (short)f2bf(v0.y);
        f[2] = (short)f2bf(v0.z); f[3] = (short)f2bf(v0.w);
        f[4] = (short)f2bf(v1.x); f[5] = (short)f2bf(v1.y);
        f[6] = (short)f2bf(v1.z); f[7] = (short)f2bf(v1.w);
        afrag[kk] = f;
    }

    const char* W = (const char*)(pass ? Wk : Wq);

    floatx4 acc[16];
#pragma unroll
    for (int ct = 0; ct < 16; ++ct) acc[ct] = (floatx4){0.f, 0.f, 0.f, 0.f};

    // Pre-stage round 0 into buf 0 (fragment-major W: round r = groups 4r..4r+3
    // = contiguous 32KB)
    {
        const char* src = W + wave * 8192;
        char* dst = lds + wave * 8192;
#pragma unroll
        for (int j = 0; j < 8; ++j) stage16(src + j * 1024, dst + j * 1024, lane);
    }

    for (int round = 0; round < 4; ++round) {
        __syncthreads();    // own-wave vmcnt drained -> buf (round&1) ready
        if (round + 1 < 4) {
            const char* src = W + (size_t)(round + 1) * 32768 + wave * 8192;
            char* dst = lds + ((round + 1) & 1) * 32768 + wave * 8192;
#pragma unroll
            for (int j = 0; j < 8; ++j) stage16(src + j * 1024, dst + j * 1024, lane);
        }
        const char* buf = lds + (round & 1) * 32768;
#pragma unroll
        for (int jt = 0; jt < 4; ++jt) {
            const int ct = round * 4 + jt;
            const char* lbase = buf + jt * 8192 + lane * 16;
            floatx4 a = acc[ct];
            __builtin_amdgcn_s_setprio(1);
#pragma unroll
            for (int kk = 0; kk < 8; ++kk) {
                short8 bfr = *(const short8*)(lbase + kk * 1024);
                a = __builtin_amdgcn_mfma_f32_16x16x32_bf16(afrag[kk], bfr, a, 0, 0, 0);
            }
            __builtin_amdgcn_s_setprio(0);
            acc[ct] = a;
        }
    }

    // Row norms (rows = quad*4 + r)
    float ss[4] = {0.f, 0.f, 0.f, 0.f};
#pragma unroll
    for (int ct = 0; ct < 16; ++ct)
#pragma unroll
        for (int r = 0; r < 4; ++r) ss[r] += acc[ct][r] * acc[ct][r];
#pragma unroll
    for (int r = 0; r < 4; ++r) {
        ss[r] += __shfl_xor(ss[r], 1, 64);
        ss[r] += __shfl_xor(ss[r], 2, 64);
        ss[r] += __shfl_xor(ss[r], 4, 64);
        ss[r] += __shfl_xor(ss[r], 8, 64);
    }
    float sc[4];
#pragma unroll
    for (int r = 0; r < 4; ++r) {
        sc[r] = 1.f / fmaxf(sqrtf(ss[r]), 1e-12f);
        if (pass == 0) sc[r] *= SCALE_LOG2E;   // fold softmax scale into qn
    }

    // Epilogue: LDS transpose (64 rows x 136-el padded bf16) then coalesced
    // 16B fragment-major stores (same verified path for qn AND kn).
    __hip_bfloat16* dstp = pass ? kn : qn;
    unsigned short* tb = (unsigned short*)lds;
#pragma unroll
    for (int h = 0; h < 2; ++h) {
        __syncthreads();   // previous lds users done
#pragma unroll
        for (int cth = 0; cth < 8; ++cth) {
            const int ct = h * 8 + cth;
            const int col = cth * 16 + n15;
#pragma unroll
            for (int r = 0; r < 4; ++r) {
                const int rl = wave * 16 + quad * 4 + r;
                tb[rl * 136 + col] = f2bf(acc[ct][r] * sc[r]);
            }
        }
        __syncthreads();
#pragma unroll
        for (int j = 0; j < 4; ++j) {
            const int g = tid + j * 256;
            const int n15r = g & 15, q2 = (g >> 4) & 3, kkh = (g >> 6) & 3, r16l = (g >> 8) & 3;
            const int rl = r16l * 16 + n15r;
            short8 v = *(const short8*)(tb + rl * 136 + kkh * 32 + q2 * 8);
            const size_t chunk = (((size_t)(r160 + r16l) * 8 + (h * 4 + kkh)) * 4 + q2) * 16 + n15r;
            *(short8*)((char*)dstp + chunk * 16) = v;
        }
    }
}

// ---------------------------------------------------------------------------
// Kernel B: flash-style attention sums — R9's conflict-free layout + rt=4.
// 256 threads = 4 waves x 64 q-rows (BM=256): each ds_read_b128 of a key
// fragment now feeds 4 MFMAs, halving per-CU LDS read traffic (20.5us ->
// 10.2us at 85B/cyc) so MFMA becomes the top pipe. This lever is NEWLY
// enabled by the fragment-major layout (R2 tried the same shape but both
// shapes were then inflated by 4.19M bank-conflict cycles).
// Live set ~210 VGPR (aq[4][8]=128 pinned + sums 48 + misc) -> natural
// 2 waves/SIMD tier -> 2 independent 4-wave blocks/CU (no launch-bounds cap;
// R6's forced cap caused a 138MB spill). The two unsynchronized blocks
// overlap MFMA vs LDS/VALU phases (m114).
// Single __syncthreads per tile (drains own tile loads), prefetch kt+1 after.
// Per-lane key accumulation order identical to R2's passing kernel ->
// absmax 0.015625. e = exp2(acc) (qn pre-scaled; clip(+-50) is a no-op).
// ---------------------------------------------------------------------------
__global__ __launch_bounds__(256) void attn_kernel(
    const __hip_bfloat16* __restrict__ qn,
    const __hip_bfloat16* __restrict__ kn,
    const float* __restrict__ coords,
    float* __restrict__ partials)
{
    __shared__ char lds[2 * 32768];

    const int tid  = threadIdx.x;
    const int wave = tid >> 6;
    const int lane = tid & 63;
    const int n15  = lane & 15;
    const int quad = lane >> 4;

    // XCD-aware bijective swizzle (512 blocks, 8 XCDs round-robin on orig id)
    int bs = (blockIdx.x & 7) * 64 + (blockIdx.x >> 3);
    const int qb    = bs % NQB;    bs /= NQB;   // XCD-contiguous ids share (b,split) kn slice
    const int split = bs % NSPLIT; bs /= NSPLIT;
    const int b     = bs;

    const int mw = b * LL + qb * BM + wave * 64;

    const int key_base = b * LL + split * KPS;
    const char* ksrc = (const char*)kn + (size_t)key_base * 512;

    // Pre-stage tile 0 (each of 4 waves stages its contiguous 8KB)
    {
        const char* src = ksrc + wave * 8192;
        char* dst = lds + wave * 8192;
#pragma unroll
        for (int j = 0; j < 8; ++j) stage16(src + j * 1024, dst + j * 1024, lane);
    }

    // Q fragments from fragment-major qn (coalesced 16B/lane), then pin.
    short8 aq[4][8];
    const int t16 = mw >> 4;
#pragma unroll
    for (int rt = 0; rt < 4; ++rt)
#pragma unroll
        for (int kk = 0; kk < 8; ++kk) {
            const size_t chunk = (((size_t)(t16 + rt) * 8 + kk) * 4 + quad) * 16 + n15;
            aq[rt][kk] = *(const short8*)((const char*)qn + chunk * 16);
        }
#pragma unroll
    for (int rt = 0; rt < 4; ++rt)
#pragma unroll
        for (int kk = 0; kk < 8; ++kk) pinv(aq[rt][kk]);

    float s0[4][4], s1[4][4], s2[4][4];
#pragma unroll
    for (int rt = 0; rt < 4; ++rt)
#pragma unroll
        for (int r = 0; r < 4; ++r) { s0[rt][r] = 0.f; s1[rt][r] = 0.f; s2[rt][r] = 0.f; }

    for (int kt = 0; kt < NKT; ++kt) {
        __syncthreads();   // own-wave vmcnt drained -> buf (kt&1) visible to all
        if (kt + 1 < NKT) {
            const char* src = ksrc + (size_t)(kt + 1) * KT * 512 + wave * 8192;
            char* dst = lds + ((kt + 1) & 1) * 32768 + wave * 8192;
#pragma unroll
            for (int j = 0; j < 8; ++j) stage16(src + j * 1024, dst + j * 1024, lane);
        }
        const char* buf = lds + (kt & 1) * 32768;

#pragma unroll
        for (int ct = 0; ct < 4; ++ct) {
            const int kidx = key_base + kt * KT + ct * 16 + n15;
            const float2 cc = *(const float2*)(coords + (size_t)kidx * 2);

            floatx4 acc[4];
#pragma unroll
            for (int rt = 0; rt < 4; ++rt) acc[rt] = (floatx4){0.f, 0.f, 0.f, 0.f};
            // fragment-major: group ct of the tile at ct*8192; lane-linear.
            const char* lbase = buf + ct * 8192 + lane * 16;

            __builtin_amdgcn_s_setprio(1);
#pragma unroll
            for (int kk = 0; kk < 8; ++kk) {
                const short8 bfr = *(const short8*)(lbase + kk * 1024);
#pragma unroll
                for (int rt = 0; rt < 4; ++rt)
                    acc[rt] = __builtin_amdgcn_mfma_f32_16x16x32_bf16(aq[rt][kk], bfr, acc[rt], 0, 0, 0);
            }
            __builtin_amdgcn_s_setprio(0);

#pragma unroll
            for (int rt = 0; rt < 4; ++rt)
#pragma unroll
                for (int r = 0; r < 4; ++r) {
                    const float e = fast_exp2(acc[rt][r]);
                    s0[rt][r] += e;
                    s1[rt][r] = fmaf(cc.x, e, s1[rt][r]);
                    s2[rt][r] = fmaf(cc.y, e, s2[rt][r]);
                }
        }
    }

    // Reduce across the 16 lanes of each quad (keys dimension)
#pragma unroll
    for (int rt = 0; rt < 4; ++rt)
#pragma unroll
        for (int r = 0; r < 4; ++r)
#pragma unroll
            for (int mask = 1; mask <= 8; mask <<= 1) {
                s0[rt][r] += __shfl_xor(s0[rt][r], mask, 64);
                s1[rt][r] += __shfl_xor(s1[rt][r], mask, 64);
                s2[rt][r] += __shfl_xor(s2[rt][r], mask, 64);
            }

    if (n15 == 0) {
#pragma unroll
        for (int rt = 0; rt < 4; ++rt)
#pragma unroll
            for (int r = 0; r < 4; ++r) {
                const int m = mw + rt * 16 + quad * 4 + r;
                float* p = partials + ((size_t)split * MM + m) * 4;
                p[0] = s0[rt][r];
                p[1] = s1[rt][r];
                p[2] = s2[rt][r];
            }
    }
}

// ---------------------------------------------------------------------------
// Kernel C: combine splits, alpha blend, emit new_coords + displacement (f32).
// ---------------------------------------------------------------------------
__global__ __launch_bounds__(256) void finish_kernel(
    const float* __restrict__ partials,
    const float* __restrict__ coords,
    const float* __restrict__ alpha_raw,
    float* __restrict__ out)
{
    const int m = blockIdx.x * 256 + threadIdx.x;

    const float alpha = 1.f / (1.f + __expf(-alpha_raw[0]));

    float s0 = 0.f, s1 = 0.f, s2 = 0.f;
#pragma unroll
    for (int s = 0; s < NSPLIT; ++s) {
        const float4 v = *(const float4*)(partials + ((size_t)s * MM + m) * 4);
        s0 += v.x; s1 += v.y; s2 += v.z;
    }

    const float cx = coords[m * 2];
    const float cy = coords[m * 2 + 1];
    const float inv = 1.f / s0;
    const float nx = alpha * (s1 * inv) + (1.f - alpha) * cx;
    const float ny = alpha * (s2 * inv) + (1.f - alpha) * cy;

    out[m * 2]     = nx;
    out[m * 2 + 1] = ny;
    out[2 * MM + m * 2]     = nx - cx;
    out[2 * MM + m * 2 + 1] = ny - cy;
}

extern "C" void kernel_launch(void* const* d_in, const int* in_sizes, int n_in,
                              void* d_out, int out_size, void* d_ws, size_t ws_size,
                              hipStream_t stream) {
    const float* latents   = (const float*)d_in[0];
    const float* coords    = (const float*)d_in[1];
    const float* Wq        = (const float*)d_in[2];
    const float* Wk        = (const float*)d_in[3];
    const float* alpha_raw = (const float*)d_in[4];
    // d_in[5] = layer_idx: selects weight set only; provided W's are the
    // pred_idx=1 params, so unused.

    char* ws = (char*)d_ws;
    __hip_bfloat16* qn   = (__hip_bfloat16*)ws;                                  // 8 MB (fragment-major)
    __hip_bfloat16* kn   = (__hip_bfloat16*)(ws + (size_t)8 * 1024 * 1024);      // 8 MB (fragment-major)
    __hip_bfloat16* wq_b = (__hip_bfloat16*)(ws + (size_t)16 * 1024 * 1024);     // 128 KB (fragment-major)
    __hip_bfloat16* wk_b = (__hip_bfloat16*)(ws + (size_t)16 * 1024 * 1024 + 131072);
    float* partials      = (float*)(ws + (size_t)16 * 1024 * 1024 + 262144);     // 2 MB

    float* out = (float*)d_out;

    cvt_fm_kernel<<<64, 256, 0, stream>>>(Wq, Wk, (unsigned short*)wq_b, (unsigned short*)wk_b);
    proj_norm_kernel<<<512, 256, 0, stream>>>(latents, wq_b, wk_b, qn, kn);
    attn_kernel<<<BB * NQB * NSPLIT, 256, 0, stream>>>(qn, kn, coords, partials);
    finish_kernel<<<MM / 256, 256, 0, stream>>>(partials, coords, alpha_raw, out);
}

// Round 11
// 129.898 us; speedup vs baseline: 1.0487x; 1.0487x over previous
//
#include <hip/hip_runtime.h>
#include <hip/hip_bf16.h>

// Problem constants
#define BB 4
#define LL 4096
#define DD 256
#define MM (BB * LL)              // 16384 rows total
#define NSPLIT 8
#define BM 256                    // query rows per attn block (8 waves x 32 rows)
#define NQB (LL / BM)             // 16 query blocks per batch
#define KPS (LL / NSPLIT)         // 512 keys per split
#define KT 64                     // keys per LDS tile (64 x 512B = 32KB)
#define NKT (KPS / KT)            // 8

typedef short short8 __attribute__((ext_vector_type(8)));   // 8 bf16 (4 VGPRs)
typedef float floatx4 __attribute__((ext_vector_type(4)));

#define SCALE_LOG2E 14.426950408889634f   // INV_TEMP * log2(e)

// Fragment-major layout (qn, kn, W all use it): for 16-row group g, the 16B
// chunk holding row (g*16+n15), k-bytes [kk*64+quad*16, +16) lives at byte
//   g*8192 + kk*1024 + quad*256 + n15*16  ==  g*8192 + kk*1024 + lane*16.
// A wave's ds_read_b128 of one kk-slice is lane-linear stride-16 (contiguous
// 1KB) -> the m97 GEMM bank pattern, zero conflicts (verified R9/R10).

__device__ __forceinline__ unsigned short f2bf(float f) {
    __hip_bfloat16 h = __float2bfloat16(f);
    union { __hip_bfloat16 h; unsigned short s; } c; c.h = h; return c.s;
}

__device__ __forceinline__ float fast_exp2(float x) {
#if __has_builtin(__builtin_amdgcn_exp2f)
    return __builtin_amdgcn_exp2f(x);
#else
    return exp2f(x);
#endif
}

// Stage 16B/lane global -> LDS (wave-uniform LDS base; lane i -> l + i*16).
__device__ __forceinline__ void stage16(const char* g, char* l, int lane) {
#if __has_builtin(__builtin_amdgcn_global_load_lds)
    __builtin_amdgcn_global_load_lds(
        (const __attribute__((address_space(1))) void*)(g + lane * 16),
        (__attribute__((address_space(3))) void*)l, 16, 0, 0);
#else
    *(short8*)(l + lane * 16) = *(const short8*)(g + lane * 16);
#endif
}

// ---------------------------------------------------------------------------
// Kernel 0: W f32 -> bf16 FRAGMENT-MAJOR. Blocks 0..31 -> Wq, 32..63 -> Wk.
// Thread t handles row r=t>>5, 8-col chunk c=t&31 (= kk*4+quad).
// ---------------------------------------------------------------------------
__global__ __launch_bounds__(256) void cvt_fm_kernel(
    const float* __restrict__ srcq, const float* __restrict__ srck,
    unsigned short* __restrict__ dstq, unsigned short* __restrict__ dstk)
{
    const int which = blockIdx.x >> 5;
    const float* src = which ? srck : srcq;
    unsigned short* dst = which ? dstk : dstq;
    const int t = (blockIdx.x & 31) * 256 + threadIdx.x;
    const int r = t >> 5, c = t & 31;
    const float4 v0 = ((const float4*)src)[t * 2];
    const float4 v1 = ((const float4*)src)[t * 2 + 1];
    short8 o;
    o[0] = (short)f2bf(v0.x); o[1] = (short)f2bf(v0.y);
    o[2] = (short)f2bf(v0.z); o[3] = (short)f2bf(v0.w);
    o[4] = (short)f2bf(v1.x); o[5] = (short)f2bf(v1.y);
    o[6] = (short)f2bf(v1.z); o[7] = (short)f2bf(v1.w);
    // chunk index = ((r>>4)*8 + kk)*4*16 + quad*16 + n15, with c = kk*4+quad
    const int chunk = (r >> 4) * 512 + c * 16 + (r & 15);
    *(short8*)(dst + (size_t)chunk * 8) = o;
}

// ---------------------------------------------------------------------------
// Kernel A: one pass (q or k) per block; 512 blocks = (row-block of 64, pass).
// Pass/pair XCD swizzle: pass = (bid>>3)&1, pair = (bid&7)|((bid>>4)<<3) ->
// the q-block and k-block of the same 64 rows land on the SAME XCD 8 ids
// apart, so the second latents read is an L2 hit (halves latents HBM).
// W staged through LDS (double-buffered, global_load_lds) from fragment-major
// W; B-fragment ds_reads are lane-linear (conflict-free).
// qn = l2norm(lat @ Wq^T)*SCALE_LOG2E, kn = l2norm(lat @ Wk^T); BOTH stored
// fragment-major via the same (verified) transpose epilogue.
// MFMA 16x16x32 bf16; C/D: col=lane&15, row=quad*4+reg.
// ---------------------------------------------------------------------------
__global__ __launch_bounds__(256) void proj_norm_kernel(
    const float* __restrict__ latents,
    const __hip_bfloat16* __restrict__ Wq,
    const __hip_bfloat16* __restrict__ Wk,
    __hip_bfloat16* __restrict__ qn,
    __hip_bfloat16* __restrict__ kn)
{
    __shared__ char lds[65536];   // 2 x 32KB W double-buffer; reused for transpose

    const int tid  = threadIdx.x;
    const int wave = tid >> 6;
    const int lane = tid & 63;
    const int n15  = lane & 15;
    const int quad = lane >> 4;

    const int pass  = (blockIdx.x >> 3) & 1;
    const int pidx  = (blockIdx.x & 7) | ((blockIdx.x >> 4) << 3);
    const int rbase = pidx * 64;
    const int m0    = rbase + wave * 16;
    const int r160  = rbase >> 4;

    // A fragments: 16 rows x K=256, f32 loaded, converted in-register
    short8 afrag[8];
    const float* Abase = latents + (size_t)(m0 + n15) * DD + quad * 8;
#pragma unroll
    for (int kk = 0; kk < 8; ++kk) {
        const float4 v0 = *(const float4*)(Abase + kk * 32);
        const float4 v1 = *(const float4*)(Abase + kk * 32 + 4);
        short8 f;
        f[0] = (short)f2bf(v0.x); f[1] = (short)f2bf(v0.y);
        f[2] = (short)f2bf(v0.z); f[3] = (short)f2bf(v0.w);
        f[4] = (short)f2bf(v1.x); f[5] = (short)f2bf(v1.y);
        f[6] = (short)f2bf(v1.z); f[7] = (short)f2bf(v1.w);
        afrag[kk] = f;
    }

    const char* W = (const char*)(pass ? Wk : Wq);

    floatx4 acc[16];
#pragma unroll
    for (int ct = 0; ct < 16; ++ct) acc[ct] = (floatx4){0.f, 0.f, 0.f, 0.f};

    // Pre-stage round 0 into buf 0 (fragment-major W: round r = groups 4r..4r+3
    // = contiguous 32KB)
    {
        const char* src = W + wave * 8192;
        char* dst = lds + wave * 8192;
#pragma unroll
        for (int j = 0; j < 8; ++j) stage16(src + j * 1024, dst + j * 1024, lane);
    }

    for (int round = 0; round < 4; ++round) {
        __syncthreads();    // own-wave vmcnt drained -> buf (round&1) ready
        if (round + 1 < 4) {
            const char* src = W + (size_t)(round + 1) * 32768 + wave * 8192;
            char* dst = lds + ((round + 1) & 1) * 32768 + wave * 8192;
#pragma unroll
            for (int j = 0; j < 8; ++j) stage16(src + j * 1024, dst + j * 1024, lane);
        }
        const char* buf = lds + (round & 1) * 32768;
#pragma unroll
        for (int jt = 0; jt < 4; ++jt) {
            const int ct = round * 4 + jt;
            const char* lbase = buf + jt * 8192 + lane * 16;
            floatx4 a = acc[ct];
            __builtin_amdgcn_s_setprio(1);
#pragma unroll
            for (int kk = 0; kk < 8; ++kk) {
                short8 bfr = *(const short8*)(lbase + kk * 1024);
                a = __builtin_amdgcn_mfma_f32_16x16x32_bf16(afrag[kk], bfr, a, 0, 0, 0);
            }
            __builtin_amdgcn_s_setprio(0);
            acc[ct] = a;
        }
    }

    // Row norms (rows = quad*4 + r)
    float ss[4] = {0.f, 0.f, 0.f, 0.f};
#pragma unroll
    for (int ct = 0; ct < 16; ++ct)
#pragma unroll
        for (int r = 0; r < 4; ++r) ss[r] += acc[ct][r] * acc[ct][r];
#pragma unroll
    for (int r = 0; r < 4; ++r) {
        ss[r] += __shfl_xor(ss[r], 1, 64);
        ss[r] += __shfl_xor(ss[r], 2, 64);
        ss[r] += __shfl_xor(ss[r], 4, 64);
        ss[r] += __shfl_xor(ss[r], 8, 64);
    }
    float sc[4];
#pragma unroll
    for (int r = 0; r < 4; ++r) {
        sc[r] = 1.f / fmaxf(sqrtf(ss[r]), 1e-12f);
        if (pass == 0) sc[r] *= SCALE_LOG2E;   // fold softmax scale into qn
    }

    // Epilogue: LDS transpose (64 rows x 136-el padded bf16) then coalesced
    // 16B fragment-major stores (same verified path for qn AND kn).
    __hip_bfloat16* dstp = pass ? kn : qn;
    unsigned short* tb = (unsigned short*)lds;
#pragma unroll
    for (int h = 0; h < 2; ++h) {
        __syncthreads();   // previous lds users done
#pragma unroll
        for (int cth = 0; cth < 8; ++cth) {
            const int ct = h * 8 + cth;
            const int col = cth * 16 + n15;
#pragma unroll
            for (int r = 0; r < 4; ++r) {
                const int rl = wave * 16 + quad * 4 + r;
                tb[rl * 136 + col] = f2bf(acc[ct][r] * sc[r]);
            }
        }
        __syncthreads();
#pragma unroll
        for (int j = 0; j < 4; ++j) {
            const int g = tid + j * 256;
            const int n15r = g & 15, q2 = (g >> 4) & 3, kkh = (g >> 6) & 3, r16l = (g >> 8) & 3;
            const int rl = r16l * 16 + n15r;
            short8 v = *(const short8*)(tb + rl * 136 + kkh * 32 + q2 * 8);
            const size_t chunk = (((size_t)(r160 + r16l) * 8 + (h * 4 + kkh)) * 4 + q2) * 16 + n15r;
            *(short8*)((char*)dstp + chunk * 16) = v;
        }
    }
}

// ---------------------------------------------------------------------------
// Kernel B: flash-style attention sums — R9's winning structure (512 thr,
// 8 waves x 32 q-rows, fragment-major conflict-free LDS reads, single
// __syncthreads-per-tile pipeline) + 4-way MFMA chain ILP.
// R10 lesson: rt=4 costs ~260 unified regs -> 1 block/CU -> slower. rt=2
// keeps ~120 regs. R9's residual stall: per ct, TWO serial 8-MFMA
// accumulation chains (latency ~145cyc vs 80cyc issue) at 2-4 waves/SIMD.
// Fix: split each chain over kk halves -> FOUR 4-MFMA chains, merged as
// exp2(accA+accB). +8 VGPRs, ~1ulp f32 reassociation before exp2
// (absmax unchanged). Everything else identical to R9.
// e = exp2(acc) (qn pre-scaled; ref's clip(+-50) is a no-op: |score|<=10).
// ---------------------------------------------------------------------------
__global__ __launch_bounds__(512) void attn_kernel(
    const __hip_bfloat16* __restrict__ qn,
    const __hip_bfloat16* __restrict__ kn,
    const float* __restrict__ coords,
    float* __restrict__ partials)
{
    __shared__ char lds[2 * 32768];

    const int tid  = threadIdx.x;
    const int wave = tid >> 6;
    const int lane = tid & 63;
    const int n15  = lane & 15;
    const int quad = lane >> 4;

    // XCD-aware bijective swizzle (512 blocks, 8 XCDs round-robin on orig id)
    int bs = (blockIdx.x & 7) * 64 + (blockIdx.x >> 3);
    const int qb    = bs % NQB;    bs /= NQB;   // XCD-contiguous ids share (b,split) kn slice
    const int split = bs % NSPLIT; bs /= NSPLIT;
    const int b     = bs;

    const int mw = b * LL + qb * BM + wave * 32;

    const int key_base = b * LL + split * KPS;
    // fragment-major: key_base is a multiple of 16; group (key_base>>4) starts
    // at byte key_base*512.
    const char* ksrc = (const char*)kn + (size_t)key_base * 512;

    // Pre-stage tile 0 (each of 8 waves stages its contiguous 4KB)
    {
        const char* src = ksrc + wave * 4096;
        char* dst = lds + wave * 4096;
#pragma unroll
        for (int j = 0; j < 4; ++j) stage16(src + j * 1024, dst + j * 1024, lane);
    }

    // Q fragments from fragment-major qn: fully coalesced 16B/lane loads
    short8 aq[2][8];
    const int t16 = mw >> 4;
#pragma unroll
    for (int rt = 0; rt < 2; ++rt)
#pragma unroll
        for (int kk = 0; kk < 8; ++kk) {
            const size_t chunk = (((size_t)(t16 + rt) * 8 + kk) * 4 + quad) * 16 + n15;
            aq[rt][kk] = *(const short8*)((const char*)qn + chunk * 16);
        }

    float s0[2][4], s1[2][4], s2[2][4];
#pragma unroll
    for (int rt = 0; rt < 2; ++rt)
#pragma unroll
        for (int r = 0; r < 4; ++r) { s0[rt][r] = 0.f; s1[rt][r] = 0.f; s2[rt][r] = 0.f; }

    for (int kt = 0; kt < NKT; ++kt) {
        __syncthreads();   // own-wave vmcnt drained -> buf (kt&1) visible to all
        if (kt + 1 < NKT) {
            const char* src = ksrc + (size_t)(kt + 1) * KT * 512 + wave * 4096;
            char* dst = lds + ((kt + 1) & 1) * 32768 + wave * 4096;
#pragma unroll
            for (int j = 0; j < 4; ++j) stage16(src + j * 1024, dst + j * 1024, lane);
        }
        const char* buf = lds + (kt & 1) * 32768;

#pragma unroll
        for (int ct = 0; ct < 4; ++ct) {
            const int kidx = key_base + kt * KT + ct * 16 + n15;
            const float2 cc = *(const float2*)(coords + (size_t)kidx * 2);

            // 4 independent MFMA chains: [rt][kk>>2] (static under unroll)
            floatx4 acc[2][2];
#pragma unroll
            for (int rt = 0; rt < 2; ++rt)
#pragma unroll
                for (int hh = 0; hh < 2; ++hh) acc[rt][hh] = (floatx4){0.f, 0.f, 0.f, 0.f};
            // fragment-major: group ct of the tile at ct*8192; lane-linear.
            const char* lbase = buf + ct * 8192 + lane * 16;
#pragma unroll
            for (int kk = 0; kk < 8; ++kk) {
                const short8 bfr = *(const short8*)(lbase + kk * 1024);
                acc[0][kk >> 2] = __builtin_amdgcn_mfma_f32_16x16x32_bf16(aq[0][kk], bfr, acc[0][kk >> 2], 0, 0, 0);
                acc[1][kk >> 2] = __builtin_amdgcn_mfma_f32_16x16x32_bf16(aq[1][kk], bfr, acc[1][kk >> 2], 0, 0, 0);
            }
#pragma unroll
            for (int r = 0; r < 4; ++r) {
                const float e0 = fast_exp2(acc[0][0][r] + acc[0][1][r]);
                const float e1 = fast_exp2(acc[1][0][r] + acc[1][1][r]);
                s0[0][r] += e0;
                s1[0][r] = fmaf(cc.x, e0, s1[0][r]);
                s2[0][r] = fmaf(cc.y, e0, s2[0][r]);
                s0[1][r] += e1;
                s1[1][r] = fmaf(cc.x, e1, s1[1][r]);
                s2[1][r] = fmaf(cc.y, e1, s2[1][r]);
            }
        }
    }

    // Reduce across the 16 lanes of each quad (keys dimension)
#pragma unroll
    for (int rt = 0; rt < 2; ++rt)
#pragma unroll
        for (int r = 0; r < 4; ++r)
#pragma unroll
            for (int mask = 1; mask <= 8; mask <<= 1) {
                s0[rt][r] += __shfl_xor(s0[rt][r], mask, 64);
                s1[rt][r] += __shfl_xor(s1[rt][r], mask, 64);
                s2[rt][r] += __shfl_xor(s2[rt][r], mask, 64);
            }

    if (n15 == 0) {
#pragma unroll
        for (int rt = 0; rt < 2; ++rt)
#pragma unroll
            for (int r = 0; r < 4; ++r) {
                const int m = mw + rt * 16 + quad * 4 + r;
                float* p = partials + ((size_t)split * MM + m) * 4;
                p[0] = s0[rt][r];
                p[1] = s1[rt][r];
                p[2] = s2[rt][r];
            }
    }
}

// ---------------------------------------------------------------------------
// Kernel C: combine splits, alpha blend, emit new_coords + displacement (f32).
// ---------------------------------------------------------------------------
__global__ __launch_bounds__(256) void finish_kernel(
    const float* __restrict__ partials,
    const float* __restrict__ coords,
    const float* __restrict__ alpha_raw,
    float* __restrict__ out)
{
    const int m = blockIdx.x * 256 + threadIdx.x;

    const float alpha = 1.f / (1.f + __expf(-alpha_raw[0]));

    float s0 = 0.f, s1 = 0.f, s2 = 0.f;
#pragma unroll
    for (int s = 0; s < NSPLIT; ++s) {
        const float4 v = *(const float4*)(partials + ((size_t)s * MM + m) * 4);
        s0 += v.x; s1 += v.y; s2 += v.z;
    }

    const float cx = coords[m * 2];
    const float cy = coords[m * 2 + 1];
    const float inv = 1.f / s0;
    const float nx = alpha * (s1 * inv) + (1.f - alpha) * cx;
    const float ny = alpha * (s2 * inv) + (1.f - alpha) * cy;

    out[m * 2]     = nx;
    out[m * 2 + 1] = ny;
    out[2 * MM + m * 2]     = nx - cx;
    out[2 * MM + m * 2 + 1] = ny - cy;
}

extern "C" void kernel_launch(void* const* d_in, const int* in_sizes, int n_in,
                              void* d_out, int out_size, void* d_ws, size_t ws_size,
                              hipStream_t stream) {
    const float* latents   = (const float*)d_in[0];
    const float* coords    = (const float*)d_in[1];
    const float* Wq        = (const float*)d_in[2];
    const float* Wk        = (const float*)d_in[3];
    const float* alpha_raw = (const float*)d_in[4];
    // d_in[5] = layer_idx: selects weight set only; provided W's are the
    // pred_idx=1 params, so unused.

    char* ws = (char*)d_ws;
    __hip_bfloat16* qn   = (__hip_bfloat16*)ws;                                  // 8 MB (fragment-major)
    __hip_bfloat16* kn   = (__hip_bfloat16*)(ws + (size_t)8 * 1024 * 1024);      // 8 MB (fragment-major)
    __hip_bfloat16* wq_b = (__hip_bfloat16*)(ws + (size_t)16 * 1024 * 1024);     // 128 KB (fragment-major)
    __hip_bfloat16* wk_b = (__hip_bfloat16*)(ws + (size_t)16 * 1024 * 1024 + 131072);
    float* partials      = (float*)(ws + (size_t)16 * 1024 * 1024 + 262144);     // 2 MB

    float* out = (float*)d_out;

    cvt_fm_kernel<<<64, 256, 0, stream>>>(Wq, Wk, (unsigned short*)wq_b, (unsigned short*)wk_b);
    proj_norm_kernel<<<512, 256, 0, stream>>>(latents, wq_b, wk_b, qn, kn);
    attn_kernel<<<BB * NQB * NSPLIT, 512, 0, stream>>>(qn, kn, coords, partials);
    finish_kernel<<<MM / 256, 256, 0, stream>>>(partials, coords, alpha_raw, out);
}

// Round 12
// 120.708 us; speedup vs baseline: 1.1285x; 1.0761x over previous
//
#include <hip/hip_runtime.h>
#include <hip/hip_bf16.h>

// Problem constants
#define BB 4
#define LL 4096
#define DD 256
#define MM (BB * LL)              // 16384 rows total
#define NSPLIT 8
#define BM 512                    // query rows per attn block (8 waves x 64 rows)
#define NQB (LL / BM)             // 8 query blocks per batch
#define KPS (LL / NSPLIT)         // 512 keys per split
#define KT 64                     // keys per LDS tile (64 x 512B = 32KB)
#define NKT (KPS / KT)            // 8

typedef short short8 __attribute__((ext_vector_type(8)));   // 8 bf16 (4 VGPRs)
typedef float floatx4 __attribute__((ext_vector_type(4)));

#define SCALE_LOG2E 14.426950408889634f   // INV_TEMP * log2(e)

// Fragment-major layout (qn, kn, W all use it): for 16-row group g, the 16B
// chunk holding row (g*16+n15), k-bytes [kk*64+quad*16, +16) lives at byte
//   g*8192 + kk*1024 + quad*256 + n15*16  ==  g*8192 + kk*1024 + lane*16.
// A wave's ds_read_b128 of one kk-slice is lane-linear stride-16 (contiguous
// 1KB) -> the m97 GEMM bank pattern, zero conflicts (verified R9/R10/R11).

__device__ __forceinline__ unsigned short f2bf(float f) {
    __hip_bfloat16 h = __float2bfloat16(f);
    union { __hip_bfloat16 h; unsigned short s; } c; c.h = h; return c.s;
}

__device__ __forceinline__ float fast_exp2(float x) {
#if __has_builtin(__builtin_amdgcn_exp2f)
    return __builtin_amdgcn_exp2f(x);
#else
    return exp2f(x);
#endif
}

// Pin a 128-bit fragment in VGPRs (defeats load-sinking/remat: round-3 showed
// the compiler re-loads Q from global inside the K-loop otherwise).
__device__ __forceinline__ void pinv(short8& v) {
    asm volatile("" : "+v"(v));
}

// Stage 16B/lane global -> LDS (wave-uniform LDS base; lane i -> l + i*16).
__device__ __forceinline__ void stage16(const char* g, char* l, int lane) {
#if __has_builtin(__builtin_amdgcn_global_load_lds)
    __builtin_amdgcn_global_load_lds(
        (const __attribute__((address_space(1))) void*)(g + lane * 16),
        (__attribute__((address_space(3))) void*)l, 16, 0, 0);
#else
    *(short8*)(l + lane * 16) = *(const short8*)(g + lane * 16);
#endif
}

// ---------------------------------------------------------------------------
// Kernel 0: W f32 -> bf16 FRAGMENT-MAJOR. Blocks 0..31 -> Wq, 32..63 -> Wk.
// Thread t handles row r=t>>5, 8-col chunk c=t&31 (= kk*4+quad).
// ---------------------------------------------------------------------------
__global__ __launch_bounds__(256) void cvt_fm_kernel(
    const float* __restrict__ srcq, const float* __restrict__ srck,
    unsigned short* __restrict__ dstq, unsigned short* __restrict__ dstk)
{
    const int which = blockIdx.x >> 5;
    const float* src = which ? srck : srcq;
    unsigned short* dst = which ? dstk : dstq;
    const int t = (blockIdx.x & 31) * 256 + threadIdx.x;
    const int r = t >> 5, c = t & 31;
    const float4 v0 = ((const float4*)src)[t * 2];
    const float4 v1 = ((const float4*)src)[t * 2 + 1];
    short8 o;
    o[0] = (short)f2bf(v0.x); o[1] = (short)f2bf(v0.y);
    o[2] = (short)f2bf(v0.z); o[3] = (short)f2bf(v0.w);
    o[4] = (short)f2bf(v1.x); o[5] = (short)f2bf(v1.y);
    o[6] = (short)f2bf(v1.z); o[7] = (short)f2bf(v1.w);
    // chunk index = ((r>>4)*8 + kk)*4*16 + quad*16 + n15, with c = kk*4+quad
    const int chunk = (r >> 4) * 512 + c * 16 + (r & 15);
    *(short8*)(dst + (size_t)chunk * 8) = o;
}

// ---------------------------------------------------------------------------
// Kernel A: one pass (q or k) per block; 512 blocks = (row-block of 64, pass).
// Pass/pair XCD swizzle: pass = (bid>>3)&1, pair = (bid&7)|((bid>>4)<<3) ->
// the q-block and k-block of the same 64 rows land on the SAME XCD 8 ids
// apart, so the second latents read is an L2 hit (halves latents HBM).
// W staged through LDS (double-buffered, global_load_lds) from fragment-major
// W; B-fragment ds_reads are lane-linear (conflict-free).
// qn = l2norm(lat @ Wq^T)*SCALE_LOG2E, kn = l2norm(lat @ Wk^T); BOTH stored
// fragment-major via the same (verified) transpose epilogue.
// MFMA 16x16x32 bf16; C/D: col=lane&15, row=quad*4+reg.
// ---------------------------------------------------------------------------
__global__ __launch_bounds__(256) void proj_norm_kernel(
    const float* __restrict__ latents,
    const __hip_bfloat16* __restrict__ Wq,
    const __hip_bfloat16* __restrict__ Wk,
    __hip_bfloat16* __restrict__ qn,
    __hip_bfloat16* __restrict__ kn)
{
    __shared__ char lds[65536];   // 2 x 32KB W double-buffer; reused for transpose

    const int tid  = threadIdx.x;
    const int wave = tid >> 6;
    const int lane = tid & 63;
    const int n15  = lane & 15;
    const int quad = lane >> 4;

    const int pass  = (blockIdx.x >> 3) & 1;
    const int pidx  = (blockIdx.x & 7) | ((blockIdx.x >> 4) << 3);
    const int rbase = pidx * 64;
    const int m0    = rbase + wave * 16;
    const int r160  = rbase >> 4;

    // A fragments: 16 rows x K=256, f32 loaded, converted in-register
    short8 afrag[8];
    const float* Abase = latents + (size_t)(m0 + n15) * DD + quad * 8;
#pragma unroll
    for (int kk = 0; kk < 8; ++kk) {
        const float4 v0 = *(const float4*)(Abase + kk * 32);
        const float4 v1 = *(const float4*)(Abase + kk * 32 + 4);
        short8 f;
        f[0] = (short)f2bf(v0.x); f[1] = (short)f2bf(v0.y);
        f[2] = (short)f2bf(v0.z); f[3] = (short)f2bf(v0.w);
        f[4] = (short)f2bf(v1.x); f[5] = (short)f2bf(v1.y);
        f[6] = (short)f2bf(v1.z); f[7] = (short)f2bf(v1.w);
        afrag[kk] = f;
    }

    const char* W = (const char*)(pass ? Wk : Wq);

    floatx4 acc[16];
#pragma unroll
    for (int ct = 0; ct < 16; ++ct) acc[ct] = (floatx4){0.f, 0.f, 0.f, 0.f};

    // Pre-stage round 0 into buf 0 (fragment-major W: round r = groups 4r..4r+3
    // = contiguous 32KB)
    {
        const char* src = W + wave * 8192;
        char* dst = lds + wave * 8192;
#pragma unroll
        for (int j = 0; j < 8; ++j) stage16(src + j * 1024, dst + j * 1024, lane);
    }

    for (int round = 0; round < 4; ++round) {
        __syncthreads();    // own-wave vmcnt drained -> buf (round&1) ready
        if (round + 1 < 4) {
            const char* src = W + (size_t)(round + 1) * 32768 + wave * 8192;
            char* dst = lds + ((round + 1) & 1) * 32768 + wave * 8192;
#pragma unroll
            for (int j = 0; j < 8; ++j) stage16(src + j * 1024, dst + j * 1024, lane);
        }
        const char* buf = lds + (round & 1) * 32768;
#pragma unroll
        for (int jt = 0; jt < 4; ++jt) {
            const int ct = round * 4 + jt;
            const char* lbase = buf + jt * 8192 + lane * 16;
            floatx4 a = acc[ct];
            __builtin_amdgcn_s_setprio(1);
#pragma unroll
            for (int kk = 0; kk < 8; ++kk) {
                short8 bfr = *(const short8*)(lbase + kk * 1024);
                a = __builtin_amdgcn_mfma_f32_16x16x32_bf16(afrag[kk], bfr, a, 0, 0, 0);
            }
            __builtin_amdgcn_s_setprio(0);
            acc[ct] = a;
        }
    }

    // Row norms (rows = quad*4 + r)
    float ss[4] = {0.f, 0.f, 0.f, 0.f};
#pragma unroll
    for (int ct = 0; ct < 16; ++ct)
#pragma unroll
        for (int r = 0; r < 4; ++r) ss[r] += acc[ct][r] * acc[ct][r];
#pragma unroll
    for (int r = 0; r < 4; ++r) {
        ss[r] += __shfl_xor(ss[r], 1, 64);
        ss[r] += __shfl_xor(ss[r], 2, 64);
        ss[r] += __shfl_xor(ss[r], 4, 64);
        ss[r] += __shfl_xor(ss[r], 8, 64);
    }
    float sc[4];
#pragma unroll
    for (int r = 0; r < 4; ++r) {
        sc[r] = 1.f / fmaxf(sqrtf(ss[r]), 1e-12f);
        if (pass == 0) sc[r] *= SCALE_LOG2E;   // fold softmax scale into qn
    }

    // Epilogue: LDS transpose (64 rows x 136-el padded bf16) then coalesced
    // 16B fragment-major stores (same verified path for qn AND kn).
    __hip_bfloat16* dstp = pass ? kn : qn;
    unsigned short* tb = (unsigned short*)lds;
#pragma unroll
    for (int h = 0; h < 2; ++h) {
        __syncthreads();   // previous lds users done
#pragma unroll
        for (int cth = 0; cth < 8; ++cth) {
            const int ct = h * 8 + cth;
            const int col = cth * 16 + n15;
#pragma unroll
            for (int r = 0; r < 4; ++r) {
                const int rl = wave * 16 + quad * 4 + r;
                tb[rl * 136 + col] = f2bf(acc[ct][r] * sc[r]);
            }
        }
        __syncthreads();
#pragma unroll
        for (int j = 0; j < 4; ++j) {
            const int g = tid + j * 256;
            const int n15r = g & 15, q2 = (g >> 4) & 3, kkh = (g >> 6) & 3, r16l = (g >> 8) & 3;
            const int rl = r16l * 16 + n15r;
            short8 v = *(const short8*)(tb + rl * 136 + kkh * 32 + q2 * 8);
            const size_t chunk = (((size_t)(r160 + r16l) * 8 + (h * 4 + kkh)) * 4 + q2) * 16 + n15r;
            *(short8*)((char*)dstp + chunk * 16) = v;
        }
    }
}

// ---------------------------------------------------------------------------
// Kernel B: flash-style attention sums — rt=4 at FULL block width.
// 512 threads = 8 waves x 64 q-rows (BM=512); grid 256 = exactly 1 block/CU.
// Rationale: per-CU LDS read volume = (waves per CU-slot) x 256KB. R9's
// 16 wave-slots x 256KB = 4MB -> 20.4us LDS floor ABOVE the 16.6us MFMA
// floor. Here 8 waves x 64 rows halves it to 2MB (10.2us), making MFMA the
// top pipe; the 32-MFMA-per-8-ds_read issue ratio (4:1) keeps the matrix
// pipe fed at 2 waves/SIMD (m97 GEMM precedent). R10's rt=4 failed at
// 256-thr blocks (1 wave/SIMD); this has 2x its residency at the same
// per-wave register budget (~210, no cap -> no spill; R6 lesson).
// Single chain per rt (R11 lesson: MFMA acc-chains don't stall; the split
// only cost registers). Single __syncthreads per tile; prefetch kt+1 after.
// Per-lane key accumulation order identical to R10's passing kernel ->
// absmax 0.015625. e = exp2(acc) (qn pre-scaled; clip(+-50) is a no-op).
// ---------------------------------------------------------------------------
__global__ __launch_bounds__(512) void attn_kernel(
    const __hip_bfloat16* __restrict__ qn,
    const __hip_bfloat16* __restrict__ kn,
    const float* __restrict__ coords,
    float* __restrict__ partials)
{
    __shared__ char lds[2 * 32768];

    const int tid  = threadIdx.x;
    const int wave = tid >> 6;
    const int lane = tid & 63;
    const int n15  = lane & 15;
    const int quad = lane >> 4;

    // XCD-aware bijective swizzle (256 blocks, 8 XCDs round-robin on orig id)
    int bs = (blockIdx.x & 7) * 32 + (blockIdx.x >> 3);
    const int qb    = bs % NQB;    bs /= NQB;   // XCD-contiguous ids share (b,split) kn slice
    const int split = bs % NSPLIT; bs /= NSPLIT;
    const int b     = bs;

    const int mw = b * LL + qb * BM + wave * 64;

    const int key_base = b * LL + split * KPS;
    const char* ksrc = (const char*)kn + (size_t)key_base * 512;

    // Pre-stage tile 0 (each of 8 waves stages its contiguous 4KB)
    {
        const char* src = ksrc + wave * 4096;
        char* dst = lds + wave * 4096;
#pragma unroll
        for (int j = 0; j < 4; ++j) stage16(src + j * 1024, dst + j * 1024, lane);
    }

    // Q fragments from fragment-major qn (coalesced 16B/lane), then pin.
    short8 aq[4][8];
    const int t16 = mw >> 4;
#pragma unroll
    for (int rt = 0; rt < 4; ++rt)
#pragma unroll
        for (int kk = 0; kk < 8; ++kk) {
            const size_t chunk = (((size_t)(t16 + rt) * 8 + kk) * 4 + quad) * 16 + n15;
            aq[rt][kk] = *(const short8*)((const char*)qn + chunk * 16);
        }
#pragma unroll
    for (int rt = 0; rt < 4; ++rt)
#pragma unroll
        for (int kk = 0; kk < 8; ++kk) pinv(aq[rt][kk]);

    float s0[4][4], s1[4][4], s2[4][4];
#pragma unroll
    for (int rt = 0; rt < 4; ++rt)
#pragma unroll
        for (int r = 0; r < 4; ++r) { s0[rt][r] = 0.f; s1[rt][r] = 0.f; s2[rt][r] = 0.f; }

    for (int kt = 0; kt < NKT; ++kt) {
        __syncthreads();   // own-wave vmcnt drained -> buf (kt&1) visible to all
        if (kt + 1 < NKT) {
            const char* src = ksrc + (size_t)(kt + 1) * KT * 512 + wave * 4096;
            char* dst = lds + ((kt + 1) & 1) * 32768 + wave * 4096;
#pragma unroll
            for (int j = 0; j < 4; ++j) stage16(src + j * 1024, dst + j * 1024, lane);
        }
        const char* buf = lds + (kt & 1) * 32768;

#pragma unroll
        for (int ct = 0; ct < 4; ++ct) {
            const int kidx = key_base + kt * KT + ct * 16 + n15;
            const float2 cc = *(const float2*)(coords + (size_t)kidx * 2);

            floatx4 acc[4];
#pragma unroll
            for (int rt = 0; rt < 4; ++rt) acc[rt] = (floatx4){0.f, 0.f, 0.f, 0.f};
            // fragment-major: group ct of the tile at ct*8192; lane-linear.
            const char* lbase = buf + ct * 8192 + lane * 16;

            __builtin_amdgcn_s_setprio(1);
#pragma unroll
            for (int kk = 0; kk < 8; ++kk) {
                const short8 bfr = *(const short8*)(lbase + kk * 1024);
#pragma unroll
                for (int rt = 0; rt < 4; ++rt)
                    acc[rt] = __builtin_amdgcn_mfma_f32_16x16x32_bf16(aq[rt][kk], bfr, acc[rt], 0, 0, 0);
            }
            __builtin_amdgcn_s_setprio(0);

#pragma unroll
            for (int rt = 0; rt < 4; ++rt)
#pragma unroll
                for (int r = 0; r < 4; ++r) {
                    const float e = fast_exp2(acc[rt][r]);
                    s0[rt][r] += e;
                    s1[rt][r] = fmaf(cc.x, e, s1[rt][r]);
                    s2[rt][r] = fmaf(cc.y, e, s2[rt][r]);
                }
        }
    }

    // Reduce across the 16 lanes of each quad (keys dimension)
#pragma unroll
    for (int rt = 0; rt < 4; ++rt)
#pragma unroll
        for (int r = 0; r < 4; ++r)
#pragma unroll
            for (int mask = 1; mask <= 8; mask <<= 1) {
                s0[rt][r] += __shfl_xor(s0[rt][r], mask, 64);
                s1[rt][r] += __shfl_xor(s1[rt][r], mask, 64);
                s2[rt][r] += __shfl_xor(s2[rt][r], mask, 64);
            }

    if (n15 == 0) {
#pragma unroll
        for (int rt = 0; rt < 4; ++rt)
#pragma unroll
            for (int r = 0; r < 4; ++r) {
                const int m = mw + rt * 16 + quad * 4 + r;
                float* p = partials + ((size_t)split * MM + m) * 4;
                p[0] = s0[rt][r];
                p[1] = s1[rt][r];
                p[2] = s2[rt][r];
            }
    }
}

// ---------------------------------------------------------------------------
// Kernel C: combine splits, alpha blend, emit new_coords + displacement (f32).
// ---------------------------------------------------------------------------
__global__ __launch_bounds__(256) void finish_kernel(
    const float* __restrict__ partials,
    const float* __restrict__ coords,
    const float* __restrict__ alpha_raw,
    float* __restrict__ out)
{
    const int m = blockIdx.x * 256 + threadIdx.x;

    const float alpha = 1.f / (1.f + __expf(-alpha_raw[0]));

    float s0 = 0.f, s1 = 0.f, s2 = 0.f;
#pragma unroll
    for (int s = 0; s < NSPLIT; ++s) {
        const float4 v = *(const float4*)(partials + ((size_t)s * MM + m) * 4);
        s0 += v.x; s1 += v.y; s2 += v.z;
    }

    const float cx = coords[m * 2];
    const float cy = coords[m * 2 + 1];
    const float inv = 1.f / s0;
    const float nx = alpha * (s1 * inv) + (1.f - alpha) * cx;
    const float ny = alpha * (s2 * inv) + (1.f - alpha) * cy;

    out[m * 2]     = nx;
    out[m * 2 + 1] = ny;
    out[2 * MM + m * 2]     = nx - cx;
    out[2 * MM + m * 2 + 1] = ny - cy;
}

extern "C" void kernel_launch(void* const* d_in, const int* in_sizes, int n_in,
                              void* d_out, int out_size, void* d_ws, size_t ws_size,
                              hipStream_t stream) {
    const float* latents   = (const float*)d_in[0];
    const float* coords    = (const float*)d_in[1];
    const float* Wq        = (const float*)d_in[2];
    const float* Wk        = (const float*)d_in[3];
    const float* alpha_raw = (const float*)d_in[4];
    // d_in[5] = layer_idx: selects weight set only; provided W's are the
    // pred_idx=1 params, so unused.

    char* ws = (char*)d_ws;
    __hip_bfloat16* qn   = (__hip_bfloat16*)ws;                                  // 8 MB (fragment-major)
    __hip_bfloat16* kn   = (__hip_bfloat16*)(ws + (size_t)8 * 1024 * 1024);      // 8 MB (fragment-major)
    __hip_bfloat16* wq_b = (__hip_bfloat16*)(ws + (size_t)16 * 1024 * 1024);     // 128 KB (fragment-major)
    __hip_bfloat16* wk_b = (__hip_bfloat16*)(ws + (size_t)16 * 1024 * 1024 + 131072);
    float* partials      = (float*)(ws + (size_t)16 * 1024 * 1024 + 262144);     // 2 MB

    float* out = (float*)d_out;

    cvt_fm_kernel<<<64, 256, 0, stream>>>(Wq, Wk, (unsigned short*)wq_b, (unsigned short*)wk_b);
    proj_norm_kernel<<<512, 256, 0, stream>>>(latents, wq_b, wk_b, qn, kn);
    attn_kernel<<<BB * NQB * NSPLIT, 512, 0, stream>>>(qn, kn, coords, partials);
    finish_kernel<<<MM / 256, 256, 0, stream>>>(partials, coords, alpha_raw, out);
}